// Round 8
// baseline (72.282 us; speedup 1.0000x reference)
//
#include <hip/hip_runtime.h>
#include <hip/hip_bf16.h>

#define N_NODES 8192
#define E_EDGES 262144
#define DIM 128
#define CAP 128                 // colbuf stride; degree ~ Poisson(32), max << 128
#define LIN_BLOCKS 512          // 16 rows each
#define SCAT_BLOCKS 768
#define SCAT_THREADS (SCAT_BLOCKS * 256)
#define FLAG_MAGIC 0x7F3D5B91   // != 0, != 0xAAAAAAAA (poison)

// Fused kernel: block 0 zeroes cursor then sets flag; scatter blocks spin on it.
//   blocks [0, LIN_BLOCKS)   -> linear (h = x @ W^T + b), h stored bf16
//   blocks [LIN_BLOCKS, ...) -> edge scatter into ushort bucket table
// Deadlock-safe: 1280 blocks * 21.5KB LDS => 7 blocks/CU => 1792 >= 1280, all
// blocks co-resident regardless of dispatch order, so block 0 always runs.
__global__ __launch_bounds__(256) void fused_scatter_linear(
        const int* __restrict__ row, const int* __restrict__ col,
        int* __restrict__ cursor, unsigned short* __restrict__ colbuf,
        const float* __restrict__ x, const float* __restrict__ W,
        const float* __restrict__ b, __hip_bfloat16* __restrict__ h,
        int* __restrict__ flag) {
    __shared__ float xsT[32][20];    // [k_local][row_local], padded
    __shared__ float wsT[32][132];   // [k_local][o], padded
    const int bx  = blockIdx.x;
    const int tid = threadIdx.x;

    if (bx == 0) {
        // zero cursor: 8192 ints = 2048 int4; 256 threads x 8 int4
        int4 z = make_int4(0, 0, 0, 0);
        int4* c4 = (int4*)cursor;
#pragma unroll
        for (int j = 0; j < 8; ++j) c4[tid + 256 * j] = z;
        __syncthreads();
        if (tid == 0) {
            __threadfence();                       // publish zeros device-wide
            atomicExch(flag, FLAG_MAGIC);          // release
        }
        // falls through to linear tile 0
    }

    if (bx >= LIN_BLOCKS) {
        // ---- scatter path: wait for cursor zeroing, then grid-stride edges ----
        if (tid == 0) {
            while (__hip_atomic_load(flag, __ATOMIC_RELAXED,
                                     __HIP_MEMORY_SCOPE_AGENT) != FLAG_MAGIC) {}
        }
        __syncthreads();       // all threads see flag observed
        __threadfence();       // acquire: cursor zeros visible
        int t = (bx - LIN_BLOCKS) * 256 + tid;
        for (int e = t; e < E_EDGES; e += SCAT_THREADS) {
            int r = row[e];
            int slot = atomicAdd(&cursor[r], 1);   // final value == degree (dups counted)
            if (slot < CAP) colbuf[(r << 7) + slot] = (unsigned short)col[e];
        }
        return;
    }

    // ---- linear path: 512 blocks, 16 rows each, 2x4 micro-tile ----
    const int r0 = bx * 16;
    const int tx = tid & 31;   // col group: cols tx*4 .. tx*4+3
    const int ty = tid >> 5;   // row group: rows ty*2 .. ty*2+1

    float acc[2][4];
#pragma unroll
    for (int i = 0; i < 2; ++i)
#pragma unroll
        for (int j = 0; j < 4; ++j) acc[i][j] = 0.0f;

    for (int kc = 0; kc < DIM; kc += 32) {
        {
            int kl = tid & 31;
            int rl = tid >> 5;  // 0..7
            xsT[kl][rl]     = x[(size_t)(r0 + rl) * DIM + kc + kl];
            xsT[kl][rl + 8] = x[(size_t)(r0 + rl + 8) * DIM + kc + kl];
        }
        {
            int o  = tid >> 1;            // 0..127
            int kb = (tid & 1) * 16;      // 0 or 16
#pragma unroll
            for (int j = 0; j < 4; ++j) {
                float4 w4 = *(const float4*)&W[(size_t)o * DIM + kc + kb + 4 * j];
                wsT[kb + 4 * j + 0][o] = w4.x;
                wsT[kb + 4 * j + 1][o] = w4.y;
                wsT[kb + 4 * j + 2][o] = w4.z;
                wsT[kb + 4 * j + 3][o] = w4.w;
            }
        }
        __syncthreads();
#pragma unroll
        for (int k = 0; k < 32; ++k) {
            float a0 = xsT[k][ty * 2];
            float a1 = xsT[k][ty * 2 + 1];
            float4 b4 = *(const float4*)&wsT[k][tx * 4];
            float bb[4] = {b4.x, b4.y, b4.z, b4.w};
#pragma unroll
            for (int j = 0; j < 4; ++j) {
                acc[0][j] += a0 * bb[j];
                acc[1][j] += a1 * bb[j];
            }
        }
        __syncthreads();
    }

    float4 bias = *(const float4*)&b[tx * 4];
#pragma unroll
    for (int i = 0; i < 2; ++i) {
        int r = r0 + ty * 2 + i;
        ushort4 o4;
        o4.x = __hip_bfloat16_raw(__float2bfloat16(acc[i][0] + bias.x)).x;
        o4.y = __hip_bfloat16_raw(__float2bfloat16(acc[i][1] + bias.y)).x;
        o4.z = __hip_bfloat16_raw(__float2bfloat16(acc[i][2] + bias.z)).x;
        o4.w = __hip_bfloat16_raw(__float2bfloat16(acc[i][3] + bias.w)).x;
        *(ushort4*)&h[((size_t)r << 7) + tx * 4] = o4;
    }
}

// out[r] = relu( sum_{unique c in adj(r)} rsqrt(deg[r])*rsqrt(deg[c]) * h[c] )
// 2048 blocks x 256 threads: 4 teams of 64 lanes, 1 row per team.
// Each lane owns dims (2*lane, 2*lane+1): ushort2 gathers, float2 store.
// Block 0 also resets the producer flag for the next replay.
__global__ __launch_bounds__(256) void aggregate_kernel(
        const int* __restrict__ deg, const unsigned short* __restrict__ colbuf,
        const __hip_bfloat16* __restrict__ h, float* __restrict__ out,
        int* __restrict__ flag) {
    __shared__ unsigned int bitmap[4][N_NODES / 32];  // 4 x 1KB
    __shared__ int   klist[4][CAP];
    __shared__ float nlist[4][CAP];
    const int bx   = blockIdx.x;
    const int tid  = threadIdx.x;
    const int team = tid >> 6;     // 0..3
    const int lane = tid & 63;
    const int r    = (bx << 2) + team;

    if (bx == 0 && tid == 0) atomicExch(flag, 0);   // re-arm for next replay

#pragma unroll
    for (int j = 0; j < 4; ++j) bitmap[team][lane * 4 + j] = 0u;
    __syncthreads();

    const int dr  = deg[r];
    const int cnt = min(dr, CAP);
    const float dinv_r = (dr > 0) ? rsqrtf((float)dr) : 0.0f;

#pragma unroll
    for (int half = 0; half < 2; ++half) {
        int s = lane + 64 * half;
        if (s < cnt) {
            int c = colbuf[(r << 7) + s];
            unsigned int bit = 1u << (c & 31);
            unsigned int old = atomicOr(&bitmap[team][c >> 5], bit);
            int dc = deg[c];                   // 32KB array -> cache-resident
            float nv = 0.0f;
            if (!(old & bit) && dc > 0) nv = dinv_r * rsqrtf((float)dc);
            klist[team][s] = c;                // uniform later load; duplicate weight = 0
            nlist[team][s] = nv;
        }
    }
    __syncthreads();

    float acc0 = 0.0f, acc1 = 0.0f;
    int i = 0;
    for (; i + 8 <= cnt; i += 8) {
#pragma unroll
        for (int j = 0; j < 8; ++j) {
            int   c = klist[team][i + j];
            float n = nlist[team][i + j];
            ushort2 hv = *(const ushort2*)&h[((size_t)c << 7) + lane * 2];
            acc0 += n * __bfloat162float(*(const __hip_bfloat16*)&hv.x);
            acc1 += n * __bfloat162float(*(const __hip_bfloat16*)&hv.y);
        }
    }
    for (; i < cnt; ++i) {
        int   c = klist[team][i];
        float n = nlist[team][i];
        ushort2 hv = *(const ushort2*)&h[((size_t)c << 7) + lane * 2];
        acc0 += n * __bfloat162float(*(const __hip_bfloat16*)&hv.x);
        acc1 += n * __bfloat162float(*(const __hip_bfloat16*)&hv.y);
    }

    float2 o2 = make_float2(fmaxf(acc0, 0.0f), fmaxf(acc1, 0.0f));
    *(float2*)&out[((size_t)r << 7) + lane * 2] = o2;
}

extern "C" void kernel_launch(void* const* d_in, const int* in_sizes, int n_in,
                              void* d_out, int out_size, void* d_ws, size_t ws_size,
                              hipStream_t stream) {
    const float* x  = (const float*)d_in[0];
    const int*   ei = (const int*)d_in[1];
    const float* W  = (const float*)d_in[2];
    const float* b  = (const float*)d_in[3];
    float* out = (float*)d_out;

    char* ws = (char*)d_ws;
    __hip_bfloat16* h = (__hip_bfloat16*)ws;                                     // 2 MB
    unsigned short* colbuf = (unsigned short*)(ws + (size_t)N_NODES * DIM * 2);  // 2 MB
    int* cursor = (int*)(ws + (size_t)N_NODES * DIM * 2 + (size_t)N_NODES * CAP * 2); // 32 KB
    int* flag   = cursor + N_NODES;

    const int* row = ei;
    const int* col = ei + E_EDGES;

    fused_scatter_linear<<<LIN_BLOCKS + SCAT_BLOCKS, 256, 0, stream>>>(
        row, col, cursor, colbuf, x, W, b, h, flag);
    aggregate_kernel<<<N_NODES / 4, 256, 0, stream>>>(cursor, colbuf, h, out, flag);
}

// Round 9
// 72.086 us; speedup vs baseline: 1.0027x; 1.0027x over previous
//
#include <hip/hip_runtime.h>
#include <hip/hip_bf16.h>

#define N_NODES 8192
#define E_EDGES 262144
#define DIM 128
#define CAP 128                 // colbuf stride; degree ~ Poisson(32), max << 128
#define LIN_BLOCKS 512          // 16 rows each
#define SCAT_BLOCKS 768
#define SCAT_THREADS (SCAT_BLOCKS * 256)
#define FLAG_MAGIC 0x7F3D5B91   // != 0, != 0xAAAAAAAA (poison)

// Fused kernel: block 0 zeroes cursor then sets flag; scatter blocks poll it
// with s_sleep throttling (R8 lesson: un-throttled spin saturates L2/vmem
// queues and starves the producer -> 60us priority inversion).
//   blocks [0, LIN_BLOCKS)   -> linear (h = x @ W^T + b), h stored bf16
//   blocks [LIN_BLOCKS, ...) -> edge scatter into ushort bucket table
// Deadlock-safe: 1280 blocks, 19.5KB LDS, 256 thr, 36 VGPR => >=5 blocks/CU
// => all 1280 co-resident regardless of dispatch order; block 0 always runs.
__global__ __launch_bounds__(256) void fused_scatter_linear(
        const int* __restrict__ row, const int* __restrict__ col,
        int* __restrict__ cursor, unsigned short* __restrict__ colbuf,
        const float* __restrict__ x, const float* __restrict__ W,
        const float* __restrict__ b, __hip_bfloat16* __restrict__ h,
        int* __restrict__ flag) {
    __shared__ float xsT[32][20];    // [k_local][row_local], padded
    __shared__ float wsT[32][132];   // [k_local][o], padded
    const int bx  = blockIdx.x;
    const int tid = threadIdx.x;

    if (bx == 0) {
        // zero cursor: 8192 ints = 2048 int4; 256 threads x 8 int4
        int4 z = make_int4(0, 0, 0, 0);
        int4* c4 = (int4*)cursor;
#pragma unroll
        for (int j = 0; j < 8; ++j) c4[tid + 256 * j] = z;
        __syncthreads();
        if (tid == 0) {
            __threadfence();                       // publish zeros to coherence point
            atomicExch(flag, FLAG_MAGIC);          // release
        }
        // falls through to linear tile 0
    }

    if (bx >= LIN_BLOCKS) {
        // ---- scatter path: throttled wait for cursor zeroing ----
        if (tid == 0) {
            while (__hip_atomic_load(flag, __ATOMIC_RELAXED,
                                     __HIP_MEMORY_SCOPE_AGENT) != FLAG_MAGIC) {
                __builtin_amdgcn_s_sleep(8);       // ~512 cy between polls
            }
        }
        __syncthreads();       // all threads see flag observed
        __threadfence();       // acquire: cursor zeros visible
        int t = (bx - LIN_BLOCKS) * 256 + tid;
        for (int e = t; e < E_EDGES; e += SCAT_THREADS) {
            int r = row[e];
            int slot = atomicAdd(&cursor[r], 1);   // final value == degree (dups counted)
            if (slot < CAP) colbuf[(r << 7) + slot] = (unsigned short)col[e];
        }
        return;
    }

    // ---- linear path: 512 blocks, 16 rows each, 2x4 micro-tile ----
    const int r0 = bx * 16;
    const int tx = tid & 31;   // col group: cols tx*4 .. tx*4+3
    const int ty = tid >> 5;   // row group: rows ty*2 .. ty*2+1

    float acc[2][4];
#pragma unroll
    for (int i = 0; i < 2; ++i)
#pragma unroll
        for (int j = 0; j < 4; ++j) acc[i][j] = 0.0f;

    for (int kc = 0; kc < DIM; kc += 32) {
        {
            int kl = tid & 31;
            int rl = tid >> 5;  // 0..7
            xsT[kl][rl]     = x[(size_t)(r0 + rl) * DIM + kc + kl];
            xsT[kl][rl + 8] = x[(size_t)(r0 + rl + 8) * DIM + kc + kl];
        }
        {
            int o  = tid >> 1;            // 0..127
            int kb = (tid & 1) * 16;      // 0 or 16
#pragma unroll
            for (int j = 0; j < 4; ++j) {
                float4 w4 = *(const float4*)&W[(size_t)o * DIM + kc + kb + 4 * j];
                wsT[kb + 4 * j + 0][o] = w4.x;
                wsT[kb + 4 * j + 1][o] = w4.y;
                wsT[kb + 4 * j + 2][o] = w4.z;
                wsT[kb + 4 * j + 3][o] = w4.w;
            }
        }
        __syncthreads();
#pragma unroll
        for (int k = 0; k < 32; ++k) {
            float a0 = xsT[k][ty * 2];
            float a1 = xsT[k][ty * 2 + 1];
            float4 b4 = *(const float4*)&wsT[k][tx * 4];
            float bb[4] = {b4.x, b4.y, b4.z, b4.w};
#pragma unroll
            for (int j = 0; j < 4; ++j) {
                acc[0][j] += a0 * bb[j];
                acc[1][j] += a1 * bb[j];
            }
        }
        __syncthreads();
    }

    float4 bias = *(const float4*)&b[tx * 4];
#pragma unroll
    for (int i = 0; i < 2; ++i) {
        int r = r0 + ty * 2 + i;
        ushort4 o4;
        o4.x = __hip_bfloat16_raw(__float2bfloat16(acc[i][0] + bias.x)).x;
        o4.y = __hip_bfloat16_raw(__float2bfloat16(acc[i][1] + bias.y)).x;
        o4.z = __hip_bfloat16_raw(__float2bfloat16(acc[i][2] + bias.z)).x;
        o4.w = __hip_bfloat16_raw(__float2bfloat16(acc[i][3] + bias.w)).x;
        *(ushort4*)&h[((size_t)r << 7) + tx * 4] = o4;
    }
}

// out[r] = relu( sum_{unique c in adj(r)} rsqrt(deg[r])*rsqrt(deg[c]) * h[c] )
// 2048 blocks x 256 threads: 4 teams of 64 lanes, 1 row per team.
// Each lane owns dims (2*lane, 2*lane+1): ushort2 gathers, float2 store.
// Block 0 also resets the producer flag for the next replay.
__global__ __launch_bounds__(256) void aggregate_kernel(
        const int* __restrict__ deg, const unsigned short* __restrict__ colbuf,
        const __hip_bfloat16* __restrict__ h, float* __restrict__ out,
        int* __restrict__ flag) {
    __shared__ unsigned int bitmap[4][N_NODES / 32];  // 4 x 1KB
    __shared__ int   klist[4][CAP];
    __shared__ float nlist[4][CAP];
    const int bx   = blockIdx.x;
    const int tid  = threadIdx.x;
    const int team = tid >> 6;     // 0..3
    const int lane = tid & 63;
    const int r    = (bx << 2) + team;

    if (bx == 0 && tid == 0) atomicExch(flag, 0);   // re-arm for next replay

#pragma unroll
    for (int j = 0; j < 4; ++j) bitmap[team][lane * 4 + j] = 0u;
    __syncthreads();

    const int dr  = deg[r];
    const int cnt = min(dr, CAP);
    const float dinv_r = (dr > 0) ? rsqrtf((float)dr) : 0.0f;

#pragma unroll
    for (int half = 0; half < 2; ++half) {
        int s = lane + 64 * half;
        if (s < cnt) {
            int c = colbuf[(r << 7) + s];
            unsigned int bit = 1u << (c & 31);
            unsigned int old = atomicOr(&bitmap[team][c >> 5], bit);
            int dc = deg[c];                   // 32KB array -> cache-resident
            float nv = 0.0f;
            if (!(old & bit) && dc > 0) nv = dinv_r * rsqrtf((float)dc);
            klist[team][s] = c;                // uniform later load; duplicate weight = 0
            nlist[team][s] = nv;
        }
    }
    __syncthreads();

    float acc0 = 0.0f, acc1 = 0.0f;
    int i = 0;
    for (; i + 8 <= cnt; i += 8) {
#pragma unroll
        for (int j = 0; j < 8; ++j) {
            int   c = klist[team][i + j];
            float n = nlist[team][i + j];
            ushort2 hv = *(const ushort2*)&h[((size_t)c << 7) + lane * 2];
            acc0 += n * __bfloat162float(*(const __hip_bfloat16*)&hv.x);
            acc1 += n * __bfloat162float(*(const __hip_bfloat16*)&hv.y);
        }
    }
    for (; i < cnt; ++i) {
        int   c = klist[team][i];
        float n = nlist[team][i];
        ushort2 hv = *(const ushort2*)&h[((size_t)c << 7) + lane * 2];
        acc0 += n * __bfloat162float(*(const __hip_bfloat16*)&hv.x);
        acc1 += n * __bfloat162float(*(const __hip_bfloat16*)&hv.y);
    }

    float2 o2 = make_float2(fmaxf(acc0, 0.0f), fmaxf(acc1, 0.0f));
    *(float2*)&out[((size_t)r << 7) + lane * 2] = o2;
}

extern "C" void kernel_launch(void* const* d_in, const int* in_sizes, int n_in,
                              void* d_out, int out_size, void* d_ws, size_t ws_size,
                              hipStream_t stream) {
    const float* x  = (const float*)d_in[0];
    const int*   ei = (const int*)d_in[1];
    const float* W  = (const float*)d_in[2];
    const float* b  = (const float*)d_in[3];
    float* out = (float*)d_out;

    char* ws = (char*)d_ws;
    __hip_bfloat16* h = (__hip_bfloat16*)ws;                                     // 2 MB
    unsigned short* colbuf = (unsigned short*)(ws + (size_t)N_NODES * DIM * 2);  // 2 MB
    int* cursor = (int*)(ws + (size_t)N_NODES * DIM * 2 + (size_t)N_NODES * CAP * 2); // 32 KB
    int* flag   = cursor + N_NODES;

    const int* row = ei;
    const int* col = ei + E_EDGES;

    fused_scatter_linear<<<LIN_BLOCKS + SCAT_BLOCKS, 256, 0, stream>>>(
        row, col, cursor, colbuf, x, W, b, h, flag);
    aggregate_kernel<<<N_NODES / 4, 256, 0, stream>>>(cursor, colbuf, h, out, flag);
}

// Round 10
// 67.566 us; speedup vs baseline: 1.0698x; 1.0669x over previous
//
#include <hip/hip_runtime.h>
#include <hip/hip_bf16.h>

#define N_NODES 8192
#define E_EDGES 262144
#define DIM 128
#define CAP 128                 // colbuf stride; degree ~ Poisson(32), max << 128
#define LIN_BLOCKS 512          // 16 rows each
#define SCAT_BLOCKS 768
#define SCAT_THREADS (SCAT_BLOCKS * 256)
#define FLAG_MAGIC 0x7F3D5B91   // != 0, != 0xAAAAAAAA (poison)

// Fused kernel: block 0 zeroes cursor then sets flag (atomicExch, executes at
// the LLC coherence point); scatter blocks poll with an atomic RMW
// (atomicAdd(flag,0)) which ALSO executes at the LLC -- immune to the per-XCD
// L2 staleness that made R8/R9's relaxed-load polls spin ~60us (poll-rate
// invariance falsified the traffic theory; non-coherent L2 serving a stale
// flag line explains it).
//   blocks [0, LIN_BLOCKS)   -> linear (h = x @ W^T + b), h stored bf16
//   blocks [LIN_BLOCKS, ...) -> edge scatter into ushort bucket table
// Deadlock-safe: 1280 blocks, 19.5KB LDS, 256 thr, 36 VGPR => 8 blocks/CU
// => all 1280 co-resident regardless of dispatch order; block 0 always runs.
__global__ __launch_bounds__(256) void fused_scatter_linear(
        const int* __restrict__ row, const int* __restrict__ col,
        int* __restrict__ cursor, unsigned short* __restrict__ colbuf,
        const float* __restrict__ x, const float* __restrict__ W,
        const float* __restrict__ b, __hip_bfloat16* __restrict__ h,
        int* __restrict__ flag) {
    __shared__ float xsT[32][20];    // [k_local][row_local], padded
    __shared__ float wsT[32][132];   // [k_local][o], padded
    const int bx  = blockIdx.x;
    const int tid = threadIdx.x;

    if (bx == 0) {
        // zero cursor: 8192 ints = 2048 int4; 256 threads x 8 int4
        int4 z = make_int4(0, 0, 0, 0);
        int4* c4 = (int4*)cursor;
#pragma unroll
        for (int j = 0; j < 8; ++j) c4[tid + 256 * j] = z;
        __syncthreads();
        if (tid == 0) {
            __threadfence();                       // publish zeros to coherence point
            atomicExch(flag, FLAG_MAGIC);          // release at LLC
        }
        // falls through to linear tile 0
    }

    if (bx >= LIN_BLOCKS) {
        // ---- scatter path ----
        // prefetch edge data (independent of cursor) before the wait
        const int t  = (bx - LIN_BLOCKS) * 256 + tid;      // t < 196608 < E
        const int e1 = t + SCAT_THREADS;
        const bool has1 = (e1 < E_EDGES);
        int r0 = row[t], c0 = col[t];
        int r1 = 0, c1 = 0;
        if (has1) { r1 = row[e1]; c1 = col[e1]; }

        if (tid == 0) {
            // RMW poll: executes at the LLC coherence point -> never stale
            while (atomicAdd(flag, 0) != FLAG_MAGIC) {
                __builtin_amdgcn_s_sleep(32);      // ~2048 cy between polls
            }
        }
        __syncthreads();       // all threads see flag observed
        __threadfence();       // acquire ordering for cursor zeros

        int slot = atomicAdd(&cursor[r0], 1);      // final value == degree (dups counted)
        if (slot < CAP) colbuf[(r0 << 7) + slot] = (unsigned short)c0;
        if (has1) {
            slot = atomicAdd(&cursor[r1], 1);
            if (slot < CAP) colbuf[(r1 << 7) + slot] = (unsigned short)c1;
        }
        return;
    }

    // ---- linear path: 512 blocks, 16 rows each, 2x4 micro-tile ----
    const int r0 = bx * 16;
    const int tx = tid & 31;   // col group: cols tx*4 .. tx*4+3
    const int ty = tid >> 5;   // row group: rows ty*2 .. ty*2+1

    float acc[2][4];
#pragma unroll
    for (int i = 0; i < 2; ++i)
#pragma unroll
        for (int j = 0; j < 4; ++j) acc[i][j] = 0.0f;

    for (int kc = 0; kc < DIM; kc += 32) {
        {
            int kl = tid & 31;
            int rl = tid >> 5;  // 0..7
            xsT[kl][rl]     = x[(size_t)(r0 + rl) * DIM + kc + kl];
            xsT[kl][rl + 8] = x[(size_t)(r0 + rl + 8) * DIM + kc + kl];
        }
        {
            int o  = tid >> 1;            // 0..127
            int kb = (tid & 1) * 16;      // 0 or 16
#pragma unroll
            for (int j = 0; j < 4; ++j) {
                float4 w4 = *(const float4*)&W[(size_t)o * DIM + kc + kb + 4 * j];
                wsT[kb + 4 * j + 0][o] = w4.x;
                wsT[kb + 4 * j + 1][o] = w4.y;
                wsT[kb + 4 * j + 2][o] = w4.z;
                wsT[kb + 4 * j + 3][o] = w4.w;
            }
        }
        __syncthreads();
#pragma unroll
        for (int k = 0; k < 32; ++k) {
            float a0 = xsT[k][ty * 2];
            float a1 = xsT[k][ty * 2 + 1];
            float4 b4 = *(const float4*)&wsT[k][tx * 4];
            float bb[4] = {b4.x, b4.y, b4.z, b4.w};
#pragma unroll
            for (int j = 0; j < 4; ++j) {
                acc[0][j] += a0 * bb[j];
                acc[1][j] += a1 * bb[j];
            }
        }
        __syncthreads();
    }

    float4 bias = *(const float4*)&b[tx * 4];
#pragma unroll
    for (int i = 0; i < 2; ++i) {
        int r = r0 + ty * 2 + i;
        ushort4 o4;
        o4.x = __hip_bfloat16_raw(__float2bfloat16(acc[i][0] + bias.x)).x;
        o4.y = __hip_bfloat16_raw(__float2bfloat16(acc[i][1] + bias.y)).x;
        o4.z = __hip_bfloat16_raw(__float2bfloat16(acc[i][2] + bias.z)).x;
        o4.w = __hip_bfloat16_raw(__float2bfloat16(acc[i][3] + bias.w)).x;
        *(ushort4*)&h[((size_t)r << 7) + tx * 4] = o4;
    }
}

// out[r] = relu( sum_{unique c in adj(r)} rsqrt(deg[r])*rsqrt(deg[c]) * h[c] )
// 2048 blocks x 256 threads: 4 teams of 64 lanes, 1 row per team.
// Each lane owns dims (2*lane, 2*lane+1): ushort2 gathers, float2 store.
// Block 0 also resets the producer flag for the next replay (RMW at LLC).
__global__ __launch_bounds__(256) void aggregate_kernel(
        const int* __restrict__ deg, const unsigned short* __restrict__ colbuf,
        const __hip_bfloat16* __restrict__ h, float* __restrict__ out,
        int* __restrict__ flag) {
    __shared__ unsigned int bitmap[4][N_NODES / 32];  // 4 x 1KB
    __shared__ int   klist[4][CAP];
    __shared__ float nlist[4][CAP];
    const int bx   = blockIdx.x;
    const int tid  = threadIdx.x;
    const int team = tid >> 6;     // 0..3
    const int lane = tid & 63;
    const int r    = (bx << 2) + team;

    if (bx == 0 && tid == 0) atomicExch(flag, 0);   // re-arm for next replay

#pragma unroll
    for (int j = 0; j < 4; ++j) bitmap[team][lane * 4 + j] = 0u;
    __syncthreads();

    const int dr  = deg[r];
    const int cnt = min(dr, CAP);
    const float dinv_r = (dr > 0) ? rsqrtf((float)dr) : 0.0f;

#pragma unroll
    for (int half = 0; half < 2; ++half) {
        int s = lane + 64 * half;
        if (s < cnt) {
            int c = colbuf[(r << 7) + s];
            unsigned int bit = 1u << (c & 31);
            unsigned int old = atomicOr(&bitmap[team][c >> 5], bit);
            int dc = deg[c];                   // 32KB array -> cache-resident
            float nv = 0.0f;
            if (!(old & bit) && dc > 0) nv = dinv_r * rsqrtf((float)dc);
            klist[team][s] = c;                // uniform later load; duplicate weight = 0
            nlist[team][s] = nv;
        }
    }
    __syncthreads();

    float acc0 = 0.0f, acc1 = 0.0f;
    int i = 0;
    for (; i + 8 <= cnt; i += 8) {
#pragma unroll
        for (int j = 0; j < 8; ++j) {
            int   c = klist[team][i + j];
            float n = nlist[team][i + j];
            ushort2 hv = *(const ushort2*)&h[((size_t)c << 7) + lane * 2];
            acc0 += n * __bfloat162float(*(const __hip_bfloat16*)&hv.x);
            acc1 += n * __bfloat162float(*(const __hip_bfloat16*)&hv.y);
        }
    }
    for (; i < cnt; ++i) {
        int   c = klist[team][i];
        float n = nlist[team][i];
        ushort2 hv = *(const ushort2*)&h[((size_t)c << 7) + lane * 2];
        acc0 += n * __bfloat162float(*(const __hip_bfloat16*)&hv.x);
        acc1 += n * __bfloat162float(*(const __hip_bfloat16*)&hv.y);
    }

    float2 o2 = make_float2(fmaxf(acc0, 0.0f), fmaxf(acc1, 0.0f));
    *(float2*)&out[((size_t)r << 7) + lane * 2] = o2;
}

extern "C" void kernel_launch(void* const* d_in, const int* in_sizes, int n_in,
                              void* d_out, int out_size, void* d_ws, size_t ws_size,
                              hipStream_t stream) {
    const float* x  = (const float*)d_in[0];
    const int*   ei = (const int*)d_in[1];
    const float* W  = (const float*)d_in[2];
    const float* b  = (const float*)d_in[3];
    float* out = (float*)d_out;

    char* ws = (char*)d_ws;
    __hip_bfloat16* h = (__hip_bfloat16*)ws;                                     // 2 MB
    unsigned short* colbuf = (unsigned short*)(ws + (size_t)N_NODES * DIM * 2);  // 2 MB
    int* cursor = (int*)(ws + (size_t)N_NODES * DIM * 2 + (size_t)N_NODES * CAP * 2); // 32 KB
    int* flag   = cursor + N_NODES;

    const int* row = ei;
    const int* col = ei + E_EDGES;

    fused_scatter_linear<<<LIN_BLOCKS + SCAT_BLOCKS, 256, 0, stream>>>(
        row, col, cursor, colbuf, x, W, b, h, flag);
    aggregate_kernel<<<N_NODES / 4, 256, 0, stream>>>(cursor, colbuf, h, out, flag);
}

// Round 11
// 41.231 us; speedup vs baseline: 1.7531x; 1.6387x over previous
//
#include <hip/hip_runtime.h>
#include <hip/hip_bf16.h>

#define N_NODES 8192
#define E_EDGES 262144
#define DIM 128
#define CAP 128                 // colbuf stride; degree ~ Poisson(32), max << 128
#define LIN_BLOCKS 512          // 16 rows each
#define SCAT_BLOCKS 768
#define SCAT_THREADS (SCAT_BLOCKS * 256)
#define FLAG_MAGIC 0x7F3D5B91   // != 0, != 0xAAAAAAAA (poison)

// FENCE-FREE producer/consumer handshake.
// R8/R9/R10 post-mortem: the ~60-77us stall was NOT poll traffic or staleness
// of the poll itself (invariant across hot-spin / throttled-load / RMW-poll).
// Common factor: __threadfence(), which on gfx94x+ (non-coherent per-XCD L2)
// emits buffer_wbl2 / buffer_inv -- 768 consumer blocks each invalidating
// their XCD's entire L2 thrashed every cache the linear path uses (same
// mechanism explains R4's ~100us/grid.sync: release+acquire fences per block).
// Fix: NO fences anywhere.
//   producer: zeroes cursor via atomicExch (RMW -> performed at the LLC
//     coherence point, never dirty in local L2), sinks returns so vmcnt
//     tracks completion, __syncthreads (waitcnt 0), then atomicExch(flag).
//   consumer: RMW-poll flag, then goes straight to atomicAdd(cursor[r],1) --
//     RMW-to-RMW at the same coherence point needs no acquire fence.
// colbuf/h are plain stores read only by the NEXT kernel (kernel-boundary
// writeback makes them visible -- proven R2-R7).
// Deadlock-safe: 1280 blocks, 19.5KB LDS, 256 thr => 8 blocks/CU capacity
// => all 1280 co-resident regardless of dispatch order; block 0 always runs.
__global__ __launch_bounds__(256) void fused_scatter_linear(
        const int* __restrict__ row, const int* __restrict__ col,
        int* __restrict__ cursor, unsigned short* __restrict__ colbuf,
        const float* __restrict__ x, const float* __restrict__ W,
        const float* __restrict__ b, __hip_bfloat16* __restrict__ h,
        int* __restrict__ flag) {
    __shared__ float xsT[32][20];    // [k_local][row_local], padded
    __shared__ float wsT[32][132];   // [k_local][o], padded
    const int bx  = blockIdx.x;
    const int tid = threadIdx.x;

    if (bx == 0) {
        // zero cursor with ATOMIC exchanges: zeros live at the LLC coherence
        // point immediately (no dirty-L2 publish problem, no wbl2 needed).
#pragma unroll
        for (int j = 0; j < 32; ++j) {
            int old = atomicExch(&cursor[tid + 256 * j], 0);
            asm volatile("" :: "v"(old));   // keep returning form; vmcnt tracks completion
        }
        __syncthreads();                    // waits vmcnt(0): all zero-RMWs performed
        if (tid == 0) atomicExch(flag, FLAG_MAGIC);   // release at LLC
        // falls through to linear tile 0
    }

    if (bx >= LIN_BLOCKS) {
        // ---- scatter path ----
        // prefetch edge data (independent of cursor) before the wait
        const int t  = (bx - LIN_BLOCKS) * 256 + tid;      // t < 196608 < E
        const int e1 = t + SCAT_THREADS;
        const bool has1 = (e1 < E_EDGES);
        int r0 = row[t], c0 = col[t];
        int r1 = 0, c1 = 0;
        if (has1) { r1 = row[e1]; c1 = col[e1]; }

        if (tid == 0) {
            // RMW poll at the LLC coherence point
            while (atomicAdd(flag, 0) != FLAG_MAGIC) {
                __builtin_amdgcn_s_sleep(8);
            }
        }
        __syncthreads();       // control gate; NO acquire fence (next access is RMW)

        int slot = atomicAdd(&cursor[r0], 1);      // final value == degree (dups counted)
        if (slot < CAP) colbuf[(r0 << 7) + slot] = (unsigned short)c0;
        if (has1) {
            slot = atomicAdd(&cursor[r1], 1);
            if (slot < CAP) colbuf[(r1 << 7) + slot] = (unsigned short)c1;
        }
        return;
    }

    // ---- linear path: 512 blocks, 16 rows each, 2x4 micro-tile ----
    const int r0 = bx * 16;
    const int tx = tid & 31;   // col group: cols tx*4 .. tx*4+3
    const int ty = tid >> 5;   // row group: rows ty*2 .. ty*2+1

    float acc[2][4];
#pragma unroll
    for (int i = 0; i < 2; ++i)
#pragma unroll
        for (int j = 0; j < 4; ++j) acc[i][j] = 0.0f;

    for (int kc = 0; kc < DIM; kc += 32) {
        {
            int kl = tid & 31;
            int rl = tid >> 5;  // 0..7
            xsT[kl][rl]     = x[(size_t)(r0 + rl) * DIM + kc + kl];
            xsT[kl][rl + 8] = x[(size_t)(r0 + rl + 8) * DIM + kc + kl];
        }
        {
            int o  = tid >> 1;            // 0..127
            int kb = (tid & 1) * 16;      // 0 or 16
#pragma unroll
            for (int j = 0; j < 4; ++j) {
                float4 w4 = *(const float4*)&W[(size_t)o * DIM + kc + kb + 4 * j];
                wsT[kb + 4 * j + 0][o] = w4.x;
                wsT[kb + 4 * j + 1][o] = w4.y;
                wsT[kb + 4 * j + 2][o] = w4.z;
                wsT[kb + 4 * j + 3][o] = w4.w;
            }
        }
        __syncthreads();
#pragma unroll
        for (int k = 0; k < 32; ++k) {
            float a0 = xsT[k][ty * 2];
            float a1 = xsT[k][ty * 2 + 1];
            float4 b4 = *(const float4*)&wsT[k][tx * 4];
            float bb[4] = {b4.x, b4.y, b4.z, b4.w};
#pragma unroll
            for (int j = 0; j < 4; ++j) {
                acc[0][j] += a0 * bb[j];
                acc[1][j] += a1 * bb[j];
            }
        }
        __syncthreads();
    }

    float4 bias = *(const float4*)&b[tx * 4];
#pragma unroll
    for (int i = 0; i < 2; ++i) {
        int r = r0 + ty * 2 + i;
        ushort4 o4;
        o4.x = __hip_bfloat16_raw(__float2bfloat16(acc[i][0] + bias.x)).x;
        o4.y = __hip_bfloat16_raw(__float2bfloat16(acc[i][1] + bias.y)).x;
        o4.z = __hip_bfloat16_raw(__float2bfloat16(acc[i][2] + bias.z)).x;
        o4.w = __hip_bfloat16_raw(__float2bfloat16(acc[i][3] + bias.w)).x;
        *(ushort4*)&h[((size_t)r << 7) + tx * 4] = o4;
    }
}

// out[r] = relu( sum_{unique c in adj(r)} rsqrt(deg[r])*rsqrt(deg[c]) * h[c] )
// 2048 blocks x 256 threads: 4 teams of 64 lanes, 1 row per team.
// Block 0 resets the producer flag for the next replay (atomic, no fence;
// kernel-boundary completion makes it visible before the next fused launch).
__global__ __launch_bounds__(256) void aggregate_kernel(
        const int* __restrict__ deg, const unsigned short* __restrict__ colbuf,
        const __hip_bfloat16* __restrict__ h, float* __restrict__ out,
        int* __restrict__ flag) {
    __shared__ unsigned int bitmap[4][N_NODES / 32];  // 4 x 1KB
    __shared__ int   klist[4][CAP];
    __shared__ float nlist[4][CAP];
    const int bx   = blockIdx.x;
    const int tid  = threadIdx.x;
    const int team = tid >> 6;     // 0..3
    const int lane = tid & 63;
    const int r    = (bx << 2) + team;

    if (bx == 0 && tid == 0) atomicExch(flag, 0);   // re-arm for next replay

#pragma unroll
    for (int j = 0; j < 4; ++j) bitmap[team][lane * 4 + j] = 0u;
    __syncthreads();

    const int dr  = deg[r];
    const int cnt = min(dr, CAP);
    const float dinv_r = (dr > 0) ? rsqrtf((float)dr) : 0.0f;

#pragma unroll
    for (int half = 0; half < 2; ++half) {
        int s = lane + 64 * half;
        if (s < cnt) {
            int c = colbuf[(r << 7) + s];
            unsigned int bit = 1u << (c & 31);
            unsigned int old = atomicOr(&bitmap[team][c >> 5], bit);
            int dc = deg[c];                   // 32KB array -> cache-resident
            float nv = 0.0f;
            if (!(old & bit) && dc > 0) nv = dinv_r * rsqrtf((float)dc);
            klist[team][s] = c;                // uniform later load; duplicate weight = 0
            nlist[team][s] = nv;
        }
    }
    __syncthreads();

    float acc0 = 0.0f, acc1 = 0.0f;
    int i = 0;
    for (; i + 8 <= cnt; i += 8) {
#pragma unroll
        for (int j = 0; j < 8; ++j) {
            int   c = klist[team][i + j];
            float n = nlist[team][i + j];
            ushort2 hv = *(const ushort2*)&h[((size_t)c << 7) + lane * 2];
            acc0 += n * __bfloat162float(*(const __hip_bfloat16*)&hv.x);
            acc1 += n * __bfloat162float(*(const __hip_bfloat16*)&hv.y);
        }
    }
    for (; i < cnt; ++i) {
        int   c = klist[team][i];
        float n = nlist[team][i];
        ushort2 hv = *(const ushort2*)&h[((size_t)c << 7) + lane * 2];
        acc0 += n * __bfloat162float(*(const __hip_bfloat16*)&hv.x);
        acc1 += n * __bfloat162float(*(const __hip_bfloat16*)&hv.y);
    }

    float2 o2 = make_float2(fmaxf(acc0, 0.0f), fmaxf(acc1, 0.0f));
    *(float2*)&out[((size_t)r << 7) + lane * 2] = o2;
}

extern "C" void kernel_launch(void* const* d_in, const int* in_sizes, int n_in,
                              void* d_out, int out_size, void* d_ws, size_t ws_size,
                              hipStream_t stream) {
    const float* x  = (const float*)d_in[0];
    const int*   ei = (const int*)d_in[1];
    const float* W  = (const float*)d_in[2];
    const float* b  = (const float*)d_in[3];
    float* out = (float*)d_out;

    char* ws = (char*)d_ws;
    __hip_bfloat16* h = (__hip_bfloat16*)ws;                                     // 2 MB
    unsigned short* colbuf = (unsigned short*)(ws + (size_t)N_NODES * DIM * 2);  // 2 MB
    int* cursor = (int*)(ws + (size_t)N_NODES * DIM * 2 + (size_t)N_NODES * CAP * 2); // 32 KB
    int* flag   = cursor + N_NODES;

    const int* row = ei;
    const int* col = ei + E_EDGES;

    fused_scatter_linear<<<LIN_BLOCKS + SCAT_BLOCKS, 256, 0, stream>>>(
        row, col, cursor, colbuf, x, W, b, h, flag);
    aggregate_kernel<<<N_NODES / 4, 256, 0, stream>>>(cursor, colbuf, h, out, flag);
}

// Round 12
// 30.839 us; speedup vs baseline: 2.3438x; 1.3369x over previous
//
#include <hip/hip_runtime.h>
#include <hip/hip_bf16.h>

#define N_NODES 8192
#define E_EDGES 262144
#define DIM 128
#define CAP 128                 // colbuf stride; degree ~ Poisson(32), max << 128
#define LIN_BLOCKS 512          // 16 rows each
#define SCAT_BLOCKS 768
#define SCAT_THREADS (SCAT_BLOCKS * 256)
#define NZB 32                  // zeroing blocks = first 32 scatter blocks
#define DONE_STRIDE 32          // ints between done slots (128B, own cacheline)
#define FLAG_MAGIC 0x7F3D5B91   // != 0, != 0xAAAAAAAA (poison)

// FENCE-FREE handshake, DISTRIBUTED zeroing.
// R11 confirmed fences were the 60-77us poison (removing them: 67.6->41.2us)
// but single-block atomic zeroing of 8192 words is queue-bound (~128 RMWs in
// flight x ~900cy => ~15-25us serialized at the LLC). Fix: 32 scatter blocks
// zero 256 words each in parallel (~1us across 32 CUs), each sets its own
// done-slot (atomicExch, MAGIC); all scatter blocks poll the 32 slots with
// threads 0-31 in parallel (RMW at LLC -- immune to per-XCD L2 staleness),
// then go straight to scatter atomicAdds. No fences anywhere.
// Poison/replay-safe: slots compared only to MAGIC; aggregate resets to 0.
// Deadlock-safe: zeroers signal BEFORE waiting; capacity 8 blocks/CU (LDS
// 19.5KB, 256thr, 36 VGPR) x 256 CU = 2048 >= 1280 -> all co-resident.
__global__ __launch_bounds__(256) void fused_scatter_linear(
        const int* __restrict__ row, const int* __restrict__ col,
        int* __restrict__ cursor, unsigned short* __restrict__ colbuf,
        const float* __restrict__ x, const float* __restrict__ W,
        const float* __restrict__ b, __hip_bfloat16* __restrict__ h,
        int* __restrict__ done) {
    __shared__ float xsT[32][20];    // [k_local][row_local], padded
    __shared__ float wsT[32][132];   // [k_local][o], padded
    const int bx  = blockIdx.x;
    const int tid = threadIdx.x;

    if (bx >= LIN_BLOCKS) {
        // ---- scatter path ----
        const int sb = bx - LIN_BLOCKS;                    // 0..767
        // prefetch edge data (independent of cursor) before the wait
        const int t  = sb * 256 + tid;                     // t < 196608 < E
        const int e1 = t + SCAT_THREADS;
        const bool has1 = (e1 < E_EDGES);
        int r0 = row[t], c0 = col[t];
        int r1 = 0, c1 = 0;
        if (has1) { r1 = row[e1]; c1 = col[e1]; }

        if (sb < NZB) {
            // zero my 256-word slice of cursor (one RMW per thread, parallel)
            int old = atomicExch(&cursor[sb * 256 + tid], 0);
            asm volatile("" :: "v"(old));      // returning form; vmcnt tracks it
            __syncthreads();                   // waitcnt vmcnt(0): zeros performed
            if (tid == 0) {
                int o2 = atomicExch(&done[sb * DONE_STRIDE], FLAG_MAGIC);
                asm volatile("" :: "v"(o2));
            }
        }

        // wait for all 32 slices: threads 0..31 poll one slot each (RMW at LLC)
        if (tid < NZB) {
            while (atomicAdd(&done[tid * DONE_STRIDE], 0) != FLAG_MAGIC) {
                __builtin_amdgcn_s_sleep(8);
            }
        }
        __syncthreads();       // control gate; no fence needed (next access is RMW)

        int slot = atomicAdd(&cursor[r0], 1);      // final value == degree (dups counted)
        if (slot < CAP) colbuf[(r0 << 7) + slot] = (unsigned short)c0;
        if (has1) {
            slot = atomicAdd(&cursor[r1], 1);
            if (slot < CAP) colbuf[(r1 << 7) + slot] = (unsigned short)c1;
        }
        return;
    }

    // ---- linear path: 512 blocks, 16 rows each, 2x4 micro-tile ----
    const int r0 = bx * 16;
    const int tx = tid & 31;   // col group: cols tx*4 .. tx*4+3
    const int ty = tid >> 5;   // row group: rows ty*2 .. ty*2+1

    float acc[2][4];
#pragma unroll
    for (int i = 0; i < 2; ++i)
#pragma unroll
        for (int j = 0; j < 4; ++j) acc[i][j] = 0.0f;

    for (int kc = 0; kc < DIM; kc += 32) {
        {
            int kl = tid & 31;
            int rl = tid >> 5;  // 0..7
            xsT[kl][rl]     = x[(size_t)(r0 + rl) * DIM + kc + kl];
            xsT[kl][rl + 8] = x[(size_t)(r0 + rl + 8) * DIM + kc + kl];
        }
        {
            int o  = tid >> 1;            // 0..127
            int kb = (tid & 1) * 16;      // 0 or 16
#pragma unroll
            for (int j = 0; j < 4; ++j) {
                float4 w4 = *(const float4*)&W[(size_t)o * DIM + kc + kb + 4 * j];
                wsT[kb + 4 * j + 0][o] = w4.x;
                wsT[kb + 4 * j + 1][o] = w4.y;
                wsT[kb + 4 * j + 2][o] = w4.z;
                wsT[kb + 4 * j + 3][o] = w4.w;
            }
        }
        __syncthreads();
#pragma unroll
        for (int k = 0; k < 32; ++k) {
            float a0 = xsT[k][ty * 2];
            float a1 = xsT[k][ty * 2 + 1];
            float4 b4 = *(const float4*)&wsT[k][tx * 4];
            float bb[4] = {b4.x, b4.y, b4.z, b4.w};
#pragma unroll
            for (int j = 0; j < 4; ++j) {
                acc[0][j] += a0 * bb[j];
                acc[1][j] += a1 * bb[j];
            }
        }
        __syncthreads();
    }

    float4 bias = *(const float4*)&b[tx * 4];
#pragma unroll
    for (int i = 0; i < 2; ++i) {
        int r = r0 + ty * 2 + i;
        ushort4 o4;
        o4.x = __hip_bfloat16_raw(__float2bfloat16(acc[i][0] + bias.x)).x;
        o4.y = __hip_bfloat16_raw(__float2bfloat16(acc[i][1] + bias.y)).x;
        o4.z = __hip_bfloat16_raw(__float2bfloat16(acc[i][2] + bias.z)).x;
        o4.w = __hip_bfloat16_raw(__float2bfloat16(acc[i][3] + bias.w)).x;
        *(ushort4*)&h[((size_t)r << 7) + tx * 4] = o4;
    }
}

// out[r] = relu( sum_{unique c in adj(r)} rsqrt(deg[r])*rsqrt(deg[c]) * h[c] )
// 2048 blocks x 256 threads: 4 teams of 64 lanes, 1 row per team.
// Block 0 resets the 32 done-slots for the next replay (atomics, no fence;
// kernel-boundary completion makes them visible before the next fused launch).
__global__ __launch_bounds__(256) void aggregate_kernel(
        const int* __restrict__ deg, const unsigned short* __restrict__ colbuf,
        const __hip_bfloat16* __restrict__ h, float* __restrict__ out,
        int* __restrict__ done) {
    __shared__ unsigned int bitmap[4][N_NODES / 32];  // 4 x 1KB
    __shared__ int   klist[4][CAP];
    __shared__ float nlist[4][CAP];
    const int bx   = blockIdx.x;
    const int tid  = threadIdx.x;
    const int team = tid >> 6;     // 0..3
    const int lane = tid & 63;
    const int r    = (bx << 2) + team;

    if (bx == 0 && tid < NZB) atomicExch(&done[tid * DONE_STRIDE], 0);  // re-arm

#pragma unroll
    for (int j = 0; j < 4; ++j) bitmap[team][lane * 4 + j] = 0u;
    __syncthreads();

    const int dr  = deg[r];
    const int cnt = min(dr, CAP);
    const float dinv_r = (dr > 0) ? rsqrtf((float)dr) : 0.0f;

#pragma unroll
    for (int half = 0; half < 2; ++half) {
        int s = lane + 64 * half;
        if (s < cnt) {
            int c = colbuf[(r << 7) + s];
            unsigned int bit = 1u << (c & 31);
            unsigned int old = atomicOr(&bitmap[team][c >> 5], bit);
            int dc = deg[c];                   // 32KB array -> cache-resident
            float nv = 0.0f;
            if (!(old & bit) && dc > 0) nv = dinv_r * rsqrtf((float)dc);
            klist[team][s] = c;                // uniform later load; duplicate weight = 0
            nlist[team][s] = nv;
        }
    }
    __syncthreads();

    float acc0 = 0.0f, acc1 = 0.0f;
    int i = 0;
    for (; i + 8 <= cnt; i += 8) {
#pragma unroll
        for (int j = 0; j < 8; ++j) {
            int   c = klist[team][i + j];
            float n = nlist[team][i + j];
            ushort2 hv = *(const ushort2*)&h[((size_t)c << 7) + lane * 2];
            acc0 += n * __bfloat162float(*(const __hip_bfloat16*)&hv.x);
            acc1 += n * __bfloat162float(*(const __hip_bfloat16*)&hv.y);
        }
    }
    for (; i < cnt; ++i) {
        int   c = klist[team][i];
        float n = nlist[team][i];
        ushort2 hv = *(const ushort2*)&h[((size_t)c << 7) + lane * 2];
        acc0 += n * __bfloat162float(*(const __hip_bfloat16*)&hv.x);
        acc1 += n * __bfloat162float(*(const __hip_bfloat16*)&hv.y);
    }

    float2 o2 = make_float2(fmaxf(acc0, 0.0f), fmaxf(acc1, 0.0f));
    *(float2*)&out[((size_t)r << 7) + lane * 2] = o2;
}

extern "C" void kernel_launch(void* const* d_in, const int* in_sizes, int n_in,
                              void* d_out, int out_size, void* d_ws, size_t ws_size,
                              hipStream_t stream) {
    const float* x  = (const float*)d_in[0];
    const int*   ei = (const int*)d_in[1];
    const float* W  = (const float*)d_in[2];
    const float* b  = (const float*)d_in[3];
    float* out = (float*)d_out;

    char* ws = (char*)d_ws;
    __hip_bfloat16* h = (__hip_bfloat16*)ws;                                     // 2 MB
    unsigned short* colbuf = (unsigned short*)(ws + (size_t)N_NODES * DIM * 2);  // 2 MB
    int* cursor = (int*)(ws + (size_t)N_NODES * DIM * 2 + (size_t)N_NODES * CAP * 2); // 32 KB
    int* done   = cursor + N_NODES;                                              // 32 slots x 128B

    const int* row = ei;
    const int* col = ei + E_EDGES;

    fused_scatter_linear<<<LIN_BLOCKS + SCAT_BLOCKS, 256, 0, stream>>>(
        row, col, cursor, colbuf, x, W, b, h, done);
    aggregate_kernel<<<N_NODES / 4, 256, 0, stream>>>(cursor, colbuf, h, out, done);
}